// Round 1
// baseline (422.410 us; speedup 1.0000x reference)
//
#include <hip/hip_runtime.h>

// Problem: S=2048, B=32, H=1024, fp32.
// energies[b,s] = dec[b,:] . (enc[s,b,:] @ W^T + bias)  -> softmax over s.
// Algebraic reduction: energies[b,s] = enc[s,b,:] . v[b,:] + c[b],
//   v[b,h] = sum_k dec[b,k] * W[k,h],  c[b] = dec[b].bias (drops out of softmax).
// So we avoid the S*B*H*H projection (137 GFLOP) and instead stream enc (256 MB) once.

#define SS 2048
#define BB 32
#define HH 1024

// v[b,h] = sum_k dec[b,k] * W[k,h].  grid = B*4 blocks, 256 thr; block = (b, 256-wide h chunk).
__global__ __launch_bounds__(256) void proj_kernel(const float* __restrict__ dec,
                                                   const float* __restrict__ W,
                                                   float* __restrict__ v) {
    __shared__ float ds[HH];
    const int b  = blockIdx.x >> 2;
    const int hc = blockIdx.x & 3;
    for (int i = threadIdx.x; i < HH; i += 256) ds[i] = dec[b * HH + i];
    __syncthreads();
    const int h = (hc << 8) + threadIdx.x;   // consecutive threads -> consecutive h: coalesced W reads
    float acc = 0.f;
    #pragma unroll 8
    for (int k = 0; k < HH; ++k) acc = fmaf(ds[k], W[k * HH + h], acc);
    v[b * HH + h] = acc;
}

// e[b,s] = enc[s,b,:] . v[b,:].  One wave per (s,b); float4 loads over contiguous H row.
__global__ __launch_bounds__(256) void energy_kernel(const float* __restrict__ enc,
                                                     const float* __restrict__ v,
                                                     float* __restrict__ e) {
    const int wid  = (blockIdx.x * 256 + threadIdx.x) >> 6;  // global wave id
    const int lane = threadIdx.x & 63;
    const int s = wid >> 5;        // wid / B
    const int b = wid & 31;        // wid % B
    const float4* ep = (const float4*)(enc + ((size_t)s * BB + b) * HH);
    const float4* vp = (const float4*)(v + (size_t)b * HH);
    float sum = 0.f;
    #pragma unroll
    for (int i = 0; i < 4; ++i) {
        float4 x = ep[i * 64 + lane];
        float4 w = vp[i * 64 + lane];
        sum += x.x * w.x + x.y * w.y + x.z * w.z + x.w * w.w;
    }
    #pragma unroll
    for (int off = 32; off > 0; off >>= 1) sum += __shfl_down(sum, off, 64);
    if (lane == 0) e[b * SS + s] = sum;
}

// In-place softmax over each row of 2048. One block (256 thr) per b.
__global__ __launch_bounds__(256) void softmax_kernel(float* __restrict__ e) {
    const int b = blockIdx.x;
    float4* p = (float4*)(e + (size_t)b * SS);
    const int t    = threadIdx.x;
    const int wave = t >> 6;
    const int lane = t & 63;
    __shared__ float red[4];

    float4 x0 = p[t];
    float4 x1 = p[t + 256];

    float m = fmaxf(fmaxf(fmaxf(x0.x, x0.y), fmaxf(x0.z, x0.w)),
                    fmaxf(fmaxf(x1.x, x1.y), fmaxf(x1.z, x1.w)));
    #pragma unroll
    for (int off = 32; off > 0; off >>= 1) m = fmaxf(m, __shfl_down(m, off, 64));
    if (lane == 0) red[wave] = m;
    __syncthreads();
    m = fmaxf(fmaxf(red[0], red[1]), fmaxf(red[2], red[3]));
    __syncthreads();   // protect red[] before reuse for the sum

    x0.x = __expf(x0.x - m); x0.y = __expf(x0.y - m);
    x0.z = __expf(x0.z - m); x0.w = __expf(x0.w - m);
    x1.x = __expf(x1.x - m); x1.y = __expf(x1.y - m);
    x1.z = __expf(x1.z - m); x1.w = __expf(x1.w - m);

    float s = (x0.x + x0.y + x0.z + x0.w) + (x1.x + x1.y + x1.z + x1.w);
    #pragma unroll
    for (int off = 32; off > 0; off >>= 1) s += __shfl_down(s, off, 64);
    if (lane == 0) red[wave] = s;
    __syncthreads();
    const float inv = 1.0f / (red[0] + red[1] + red[2] + red[3]);

    x0.x *= inv; x0.y *= inv; x0.z *= inv; x0.w *= inv;
    x1.x *= inv; x1.y *= inv; x1.z *= inv; x1.w *= inv;
    p[t]       = x0;
    p[t + 256] = x1;
}

extern "C" void kernel_launch(void* const* d_in, const int* in_sizes, int n_in,
                              void* d_out, int out_size, void* d_ws, size_t ws_size,
                              hipStream_t stream) {
    const float* rnn = (const float*)d_in[0];   // [1,B,H]
    const float* enc = (const float*)d_in[1];   // [S,B,H]
    const float* W   = (const float*)d_in[2];   // [H,H]
    // d_in[3] = b_attn: contributes a per-b constant to energies -> cancels in softmax.
    float* out = (float*)d_out;                 // [B,S]
    float* v   = (float*)d_ws;                  // [B,H] scratch (128 KB)

    proj_kernel<<<BB * 4, 256, 0, stream>>>(rnn, W, v);
    energy_kernel<<<(SS * BB) / 4, 256, 0, stream>>>(enc, v, out);
    softmax_kernel<<<BB, 256, 0, stream>>>(out);
}

// Round 3
// 416.491 us; speedup vs baseline: 1.0142x; 1.0142x over previous
//
#include <hip/hip_runtime.h>

// Problem: S=2048, B=32, H=1024, fp32.
// energies[b,s] = dec[b,:] . (enc[s,b,:] @ W^T + bias)  -> softmax over s.
// Algebraic reduction: energies[b,s] = enc[s,b,:] . v[b,:] + c[b],
//   v[b,h] = sum_k dec[b,k] * W[k,h],  c[b] = dec[b].bias (constant per row -> cancels in softmax).
// Floor: one 256 MB stream of enc @ ~6.3 TB/s ≈ 41 us. proj/softmax are noise.

#define SS 2048
#define BB 32
#define HH 1024

typedef float vfloat4 __attribute__((ext_vector_type(4)));  // native vec: ok for nontemporal builtin

// v[b,h] = sum_k dec[b,k] * W[k,h].  One block per b; thread t owns h=4t..4t+3 (float4).
// 2 accumulator sets break the fp add chain; W loads coalesced 4KB per k-row.
__global__ __launch_bounds__(256) void proj_kernel(const float* __restrict__ dec,
                                                   const float* __restrict__ W,
                                                   float* __restrict__ v) {
    __shared__ float ds[HH];
    const int b = blockIdx.x;
    for (int i = threadIdx.x; i < HH; i += 256) ds[i] = dec[b * HH + i];
    __syncthreads();
    const int t = threadIdx.x;
    const vfloat4* Wv = (const vfloat4*)W;           // row k = Wv[k*256 + t]
    vfloat4 a0 = {0.f, 0.f, 0.f, 0.f};
    vfloat4 a1 = {0.f, 0.f, 0.f, 0.f};
    #pragma unroll 4
    for (int k = 0; k < HH; k += 2) {
        const float s0 = ds[k], s1 = ds[k + 1];
        const vfloat4 w0 = Wv[(size_t)k * 256 + t];
        const vfloat4 w1 = Wv[(size_t)(k + 1) * 256 + t];
        a0.x = fmaf(s0, w0.x, a0.x); a0.y = fmaf(s0, w0.y, a0.y);
        a0.z = fmaf(s0, w0.z, a0.z); a0.w = fmaf(s0, w0.w, a0.w);
        a1.x = fmaf(s1, w1.x, a1.x); a1.y = fmaf(s1, w1.y, a1.y);
        a1.z = fmaf(s1, w1.z, a1.z); a1.w = fmaf(s1, w1.w, a1.w);
    }
    vfloat4 r = a0 + a1;
    ((vfloat4*)(v + (size_t)b * HH))[t] = r;
}

// e[b,s] = enc[s,b,:] . v[b,:].  One wave per (s,b); 16B loads over contiguous H row.
// enc is streamed once (no reuse) -> nontemporal loads keep v/W from being evicted.
__global__ __launch_bounds__(256) void energy_kernel(const float* __restrict__ enc,
                                                     const float* __restrict__ v,
                                                     float* __restrict__ e) {
    const int wid  = (blockIdx.x * 256 + threadIdx.x) >> 6;  // global wave id
    const int lane = threadIdx.x & 63;
    const int s = wid >> 5;        // wid / B
    const int b = wid & 31;        // wid % B
    const vfloat4* ep = (const vfloat4*)(enc + ((size_t)s * BB + b) * HH);
    const vfloat4* vp = (const vfloat4*)(v + (size_t)b * HH);
    float sum = 0.f;
    #pragma unroll
    for (int i = 0; i < 4; ++i) {
        vfloat4 x = __builtin_nontemporal_load(&ep[i * 64 + lane]);
        vfloat4 w = vp[i * 64 + lane];
        sum += x.x * w.x + x.y * w.y + x.z * w.z + x.w * w.w;
    }
    #pragma unroll
    for (int off = 32; off > 0; off >>= 1) sum += __shfl_down(sum, off, 64);
    if (lane == 0) e[b * SS + s] = sum;
}

// In-place softmax over each row of 2048. One block (256 thr) per b.
__global__ __launch_bounds__(256) void softmax_kernel(float* __restrict__ e) {
    const int b = blockIdx.x;
    vfloat4* p = (vfloat4*)(e + (size_t)b * SS);
    const int t    = threadIdx.x;
    const int wave = t >> 6;
    const int lane = t & 63;
    __shared__ float red[4];

    vfloat4 x0 = p[t];
    vfloat4 x1 = p[t + 256];

    float m = fmaxf(fmaxf(fmaxf(x0.x, x0.y), fmaxf(x0.z, x0.w)),
                    fmaxf(fmaxf(x1.x, x1.y), fmaxf(x1.z, x1.w)));
    #pragma unroll
    for (int off = 32; off > 0; off >>= 1) m = fmaxf(m, __shfl_down(m, off, 64));
    if (lane == 0) red[wave] = m;
    __syncthreads();
    m = fmaxf(fmaxf(red[0], red[1]), fmaxf(red[2], red[3]));
    __syncthreads();   // protect red[] before reuse for the sum

    x0.x = __expf(x0.x - m); x0.y = __expf(x0.y - m);
    x0.z = __expf(x0.z - m); x0.w = __expf(x0.w - m);
    x1.x = __expf(x1.x - m); x1.y = __expf(x1.y - m);
    x1.z = __expf(x1.z - m); x1.w = __expf(x1.w - m);

    float s = (x0.x + x0.y + x0.z + x0.w) + (x1.x + x1.y + x1.z + x1.w);
    #pragma unroll
    for (int off = 32; off > 0; off >>= 1) s += __shfl_down(s, off, 64);
    if (lane == 0) red[wave] = s;
    __syncthreads();
    const float inv = 1.0f / (red[0] + red[1] + red[2] + red[3]);

    x0 *= inv;
    x1 *= inv;
    p[t]       = x0;
    p[t + 256] = x1;
}

extern "C" void kernel_launch(void* const* d_in, const int* in_sizes, int n_in,
                              void* d_out, int out_size, void* d_ws, size_t ws_size,
                              hipStream_t stream) {
    const float* rnn = (const float*)d_in[0];   // [1,B,H]
    const float* enc = (const float*)d_in[1];   // [S,B,H]
    const float* W   = (const float*)d_in[2];   // [H,H]
    // d_in[3] = b_attn: adds a per-b constant to energies -> cancels in softmax.
    float* out = (float*)d_out;                 // [B,S]
    float* v   = (float*)d_ws;                  // [B,H] scratch (128 KB)

    proj_kernel<<<BB, 256, 0, stream>>>(rnn, W, v);
    energy_kernel<<<(SS * BB) / 4, 256, 0, stream>>>(enc, v, out);
    softmax_kernel<<<BB, 256, 0, stream>>>(out);
}

// Round 4
// 363.145 us; speedup vs baseline: 1.1632x; 1.1469x over previous
//
#include <hip/hip_runtime.h>

// Problem: S=2048, B=32, H=1024, fp32.
// energies[b,s] = dec[b,:] . (enc[s,b,:] @ W^T + bias)  -> softmax over s.
// Algebraic reduction: energies[b,s] = enc[s,b,:] . v[b,:] + c[b],
//   v[b,h] = sum_k dec[b,k] * W[k,h],  c[b] = dec[b].bias (constant per row -> cancels in softmax).
// Floor: one 256 MB stream of enc @ ~6.3 TB/s ≈ 41 us. proj/softmax are noise.

#define SS 2048
#define BB 32
#define HH 1024

typedef float vfloat4 __attribute__((ext_vector_type(4)));  // native vec: ok for nontemporal builtin

// v[b,h] = sum_k dec[b,k] * W[k,h].
// grid = 256 blocks = (b, hc): hc selects a 128-wide h chunk; 2-way k-split within the
// block (threads 0-127 do k<512 on h, threads 128-255 do k>=512 on the same h), LDS combine.
// Each block reads only 512 KB of W -> all 256 CUs active, per-CU L2 pull is small.
// ds[] reads are wave-uniform (broadcast, conflict-free); W reads coalesced.
__global__ __launch_bounds__(256) void proj_kernel(const float* __restrict__ dec,
                                                   const float* __restrict__ W,
                                                   float* __restrict__ v) {
    __shared__ float ds[HH];
    __shared__ float part[256];
    const int b  = blockIdx.x >> 3;
    const int hc = blockIdx.x & 7;
    for (int i = threadIdx.x; i < HH; i += 256) ds[i] = dec[b * HH + i];
    __syncthreads();
    const int t  = threadIdx.x;
    const int h  = (hc << 7) + (t & 127);
    const int k0 = (t >> 7) << 9;            // 0 or 512
    float a0 = 0.f, a1 = 0.f;
    #pragma unroll 8
    for (int k = 0; k < 512; k += 2) {
        a0 = fmaf(ds[k0 + k],     W[(size_t)(k0 + k) * HH + h],     a0);
        a1 = fmaf(ds[k0 + k + 1], W[(size_t)(k0 + k + 1) * HH + h], a1);
    }
    part[t] = a0 + a1;
    __syncthreads();
    if (t < 128) v[b * HH + h] = part[t] + part[t + 128];
}

// e[b,s] = enc[s,b,:] . v[b,:].  One wave per (s,b); 16B loads over contiguous H row.
// enc is streamed once (no reuse) -> nontemporal loads keep v/W from being evicted.
__global__ __launch_bounds__(256) void energy_kernel(const float* __restrict__ enc,
                                                     const float* __restrict__ v,
                                                     float* __restrict__ e) {
    const int wid  = (blockIdx.x * 256 + threadIdx.x) >> 6;  // global wave id
    const int lane = threadIdx.x & 63;
    const int s = wid >> 5;        // wid / B
    const int b = wid & 31;        // wid % B
    const vfloat4* ep = (const vfloat4*)(enc + ((size_t)s * BB + b) * HH);
    const vfloat4* vp = (const vfloat4*)(v + (size_t)b * HH);
    float sum = 0.f;
    #pragma unroll
    for (int i = 0; i < 4; ++i) {
        vfloat4 x = __builtin_nontemporal_load(&ep[i * 64 + lane]);
        vfloat4 w = vp[i * 64 + lane];
        sum += x.x * w.x + x.y * w.y + x.z * w.z + x.w * w.w;
    }
    #pragma unroll
    for (int off = 32; off > 0; off >>= 1) sum += __shfl_down(sum, off, 64);
    if (lane == 0) e[b * SS + s] = sum;
}

// In-place softmax over each row of 2048. One block (256 thr) per b.
__global__ __launch_bounds__(256) void softmax_kernel(float* __restrict__ e) {
    const int b = blockIdx.x;
    vfloat4* p = (vfloat4*)(e + (size_t)b * SS);
    const int t    = threadIdx.x;
    const int wave = t >> 6;
    const int lane = t & 63;
    __shared__ float red[4];

    vfloat4 x0 = p[t];
    vfloat4 x1 = p[t + 256];

    float m = fmaxf(fmaxf(fmaxf(x0.x, x0.y), fmaxf(x0.z, x0.w)),
                    fmaxf(fmaxf(x1.x, x1.y), fmaxf(x1.z, x1.w)));
    #pragma unroll
    for (int off = 32; off > 0; off >>= 1) m = fmaxf(m, __shfl_down(m, off, 64));
    if (lane == 0) red[wave] = m;
    __syncthreads();
    m = fmaxf(fmaxf(red[0], red[1]), fmaxf(red[2], red[3]));
    __syncthreads();   // protect red[] before reuse for the sum

    x0.x = __expf(x0.x - m); x0.y = __expf(x0.y - m);
    x0.z = __expf(x0.z - m); x0.w = __expf(x0.w - m);
    x1.x = __expf(x1.x - m); x1.y = __expf(x1.y - m);
    x1.z = __expf(x1.z - m); x1.w = __expf(x1.w - m);

    float s = (x0.x + x0.y + x0.z + x0.w) + (x1.x + x1.y + x1.z + x1.w);
    #pragma unroll
    for (int off = 32; off > 0; off >>= 1) s += __shfl_down(s, off, 64);
    if (lane == 0) red[wave] = s;
    __syncthreads();
    const float inv = 1.0f / (red[0] + red[1] + red[2] + red[3]);

    x0 *= inv;
    x1 *= inv;
    p[t]       = x0;
    p[t + 256] = x1;
}

extern "C" void kernel_launch(void* const* d_in, const int* in_sizes, int n_in,
                              void* d_out, int out_size, void* d_ws, size_t ws_size,
                              hipStream_t stream) {
    const float* rnn = (const float*)d_in[0];   // [1,B,H]
    const float* enc = (const float*)d_in[1];   // [S,B,H]
    const float* W   = (const float*)d_in[2];   // [H,H]
    // d_in[3] = b_attn: adds a per-b constant to energies -> cancels in softmax.
    float* out = (float*)d_out;                 // [B,S]
    float* v   = (float*)d_ws;                  // [B,H] scratch (128 KB)

    proj_kernel<<<BB * 8, 256, 0, stream>>>(rnn, W, v);
    energy_kernel<<<(SS * BB) / 4, 256, 0, stream>>>(enc, v, out);
    softmax_kernel<<<BB, 256, 0, stream>>>(out);
}